// Round 14
// baseline (73.666 us; speedup 1.0000x reference)
//
#include <hip/hip_runtime.h>
#include <hip/hip_bf16.h>

typedef short short8 __attribute__((ext_vector_type(8)));
typedef float f32x4 __attribute__((ext_vector_type(4)));
typedef int   i32x4 __attribute__((ext_vector_type(4)));
typedef unsigned short ushort_t;
typedef unsigned short ushort4v __attribute__((ext_vector_type(4)));

#define NBLK   2048
#define ROWCAP 96
#define PCAP   192
#define ZBLK   2048          // zero weight block index
#define ZENTP  ((ZBLK << 6) | (ZBLK << 18))   // pair-list pad: col0, both zero blocks
#define MFMA_BF16 __builtin_amdgcn_mfma_f32_16x16x32_bf16

__device__ __forceinline__ ushort_t f2bf(float f) {
    unsigned u = __float_as_uint(f);
    u += 0x7FFFu + ((u >> 16) & 1u);   // RTNE
    return (ushort_t)(u >> 16);
}
__device__ __forceinline__ void gll16(const void* g, void* l) {
    __builtin_amdgcn_global_load_lds(
        (const __attribute__((address_space(1))) unsigned*)g,
        (__attribute__((address_space(3))) unsigned*)l, 16, 0, 0);
}

// ================= prep 1 (verbatim R8, passed) =================
__global__ __launch_bounds__(256)
void prep_kernel(const float* __restrict__ x, const float* __restrict__ wblk,
                 const int* __restrict__ brows, const int* __restrict__ bcols,
                 ushort_t* __restrict__ xc, ushort_t* __restrict__ wb,
                 int* __restrict__ bucket, int* __restrict__ bcnt) {
    __shared__ ushort_t pt[4][2048];
    const int bid = blockIdx.x, tid = threadIdx.x;
    const int wv = tid >> 6, lane = tid & 63;

    if (bid < 1024) {
        const int tc = bid * 4 + wv;
        const int cb = tc >> 6, t64 = tc & 63;
        #pragma unroll
        for (int it = 0; it < 8; ++it) {
            int row = it * 8 + (lane >> 3);
            const float* src = x + (size_t)(t64 * 64 + row) * 2048 + cb * 32 + (lane & 7) * 4;
            float4 v = *reinterpret_cast<const float4*>(src);
            ushort4v o; o.x = f2bf(v.x); o.y = f2bf(v.y); o.z = f2bf(v.z); o.w = f2bf(v.w);
            int m = row >> 4, l15v = row & 15, hi = (lane & 7) >> 1;
            int cc = m * 64 + hi * 16 + l15v;
            *reinterpret_cast<ushort4v*>(&pt[wv][cc * 8 + (lane & 1) * 4]) = o;
        }
        #pragma unroll
        for (int rr = 0; rr < 4; ++rr) {
            i32x4 d = *reinterpret_cast<const i32x4*>(&pt[wv][(rr * 64 + lane) * 8]);
            *reinterpret_cast<i32x4*>(xc + (size_t)tc * 2048 + (rr * 64 + lane) * 8) = d;
        }
    } else if (bid < 2048) {
        int d = (bid - 1024) * 256 + tid;
        int n = d >> 7, cc = d & 127;
        int nsub = cc >> 6, ln = cc & 63;
        int o_ = nsub * 16 + (ln & 15), kc = ln >> 4;
        const float* src = wblk + (size_t)n * 1024 + o_ * 32 + kc * 8;
        float4 v0 = *reinterpret_cast<const float4*>(src);
        float4 v1 = *reinterpret_cast<const float4*>(src + 4);
        short8 o8;
        o8[0] = f2bf(v0.x); o8[1] = f2bf(v0.y); o8[2] = f2bf(v0.z); o8[3] = f2bf(v0.w);
        o8[4] = f2bf(v1.x); o8[5] = f2bf(v1.y); o8[6] = f2bf(v1.z); o8[7] = f2bf(v1.w);
        reinterpret_cast<short8*>(wb)[d] = o8;
    } else if (bid == 2048) {
        if (tid < 128) {
            short8 z = (short8){0,0,0,0,0,0,0,0};
            reinterpret_cast<short8*>(wb + (size_t)ZBLK * 1024)[tid] = z;
        }
    } else {
        const int r = (bid - 2049) * 4 + wv;
        const int per = NBLK / 64;
        const int base = lane * per;
        int cnt = 0;
        for (int k = 0; k < per; ++k) cnt += (brows[base + k] == r) ? 1 : 0;
        int sum = cnt;
        for (int d = 1; d < 64; d <<= 1) {
            int v = __shfl_up(sum, d, 64);
            if (lane >= d) sum += v;
        }
        int off = sum - cnt;
        for (int k = 0; k < per; ++k) {
            int n = base + k;
            if (brows[n] == r) bucket[r * ROWCAP + (off++)] = (n << 6) | bcols[n];
        }
        int total = __shfl(sum, 63, 64);
        if (lane == 0) bcnt[r] = total;
    }
}

// ================= prep 2: merge row pairs into column-sorted entry lists =================
// plist[p][k] = col(6b) | n0<<6 (12b) | n1<<18 (12b); missing side -> ZBLK (zero block).
__global__ __launch_bounds__(64)
void prep2_kernel(const int* __restrict__ bucket, const int* __restrict__ bcnt,
                  int* __restrict__ plist, int* __restrict__ pcnt) {
    __shared__ int s0[96], s1[96];
    const int p = blockIdx.x, lane = threadIdx.x;
    const int c0 = bcnt[p * 2], c1 = bcnt[p * 2 + 1];

    // counting-rank sort each row's list by (col, idx)  [R6-proven]
    {
        int e   = (lane < c0) ? bucket[(p * 2) * ROWCAP + lane] : 0;
        int key = (lane < c0) ? (((e & 63) << 7) | lane) : 0x7FFFFFFF;
        int rank = 0;
        for (int j = 0; j < 64; ++j) { int kj = __shfl(key, j, 64); rank += (kj < key) ? 1 : 0; }
        if (lane < c0) s0[rank] = e;
    }
    {
        int e   = (lane < c1) ? bucket[(p * 2 + 1) * ROWCAP + lane] : 0;
        int key = (lane < c1) ? (((e & 63) << 7) | lane) : 0x7FFFFFFF;
        int rank = 0;
        for (int j = 0; j < 64; ++j) { int kj = __shfl(key, j, 64); rank += (kj < key) ? 1 : 0; }
        if (lane < c1) s1[rank] = e;
    }
    __syncthreads();

    // lane c owns column c: multiplicities + start offsets in the sorted lists
    const int c = lane;
    int m0 = 0, st0 = 0, m1 = 0, st1 = 0;
    for (int k = 0; k < c0; ++k) { int cc = s0[k] & 63; m0 += (cc == c); st0 += (cc < c); }
    for (int k = 0; k < c1; ++k) { int cc = s1[k] & 63; m1 += (cc == c); st1 += (cc < c); }
    int mc = (m0 > m1) ? m0 : m1;

    int sum = mc;
    for (int d = 1; d < 64; d <<= 1) {
        int t = __shfl_up(sum, d, 64);
        if (lane >= d) sum += t;
    }
    int base = sum - mc;
    int total = __shfl(sum, 63, 64);

    for (int k = 0; k < mc; ++k) {
        int n0 = (k < m0) ? (s0[st0 + k] >> 6) : ZBLK;
        int n1 = (k < m1) ? (s1[st1 + k] >> 6) : ZBLK;
        plist[p * PCAP + base + k] = c | (n0 << 6) | (n1 << 18);
    }
    if (lane < 8) plist[p * PCAP + total + lane] = ZENTP;   // pads (zero blocks, col 0)
    if (lane == 0) pcnt[p] = ((total + 2) / 3) * 3;
}

// ================= main kernel: row-pair waves, private depth-3 rings =================
// 512 WGs x 128 thr (2 waves). Wave job = (row-PAIR, 128-token slab), R13 XCD map
// (q=slabgroup -> A slice 2 MB L2-pinned). Per entry: A panel shared by both rows.
// 12 gll16/subiter uniform (8 A + 2x2 B, zero-block for missing side = L2-hot dup).
// Counted vmcnt(12), stage-ahead 2, no barriers. 32 MFMA/subiter into acc0/acc1.
#define DSR(d, a, o) asm volatile("ds_read_b128 %0, %1 offset:" #o : "=v"(d) : "v"(a))

#define SUBITER(FA, FB, SPA, SPB, EX) do {                                     \
    short8 a0,a1,a2,a3,a4,a5,a6,a7,b00,b01,b10,b11;                            \
    asm volatile("s_waitcnt vmcnt(12)" ::: "memory");                          \
    DSR(a0, FA, 0);    DSR(a1, FA, 1024); DSR(a2, FA, 2048); DSR(a3, FA, 3072);\
    DSR(a4, FA, 4096); DSR(a5, FA, 5120); DSR(a6, FA, 6144); DSR(a7, FA, 7168);\
    DSR(b00, FB, 0);   DSR(b01, FB, 1024); DSR(b10, FB, 2048); DSR(b11, FB, 3072);\
    STAGE(SPA, SPB, EX);                                                       \
    asm volatile("ds_read_b32 %0, %1" : "=v"(EX) : "v"(laddr) : "memory");     \
    laddr += 4;                                                                \
    asm volatile("s_waitcnt lgkmcnt(0)" ::: "memory");                         \
    __builtin_amdgcn_sched_barrier(0);                                         \
    __builtin_amdgcn_s_setprio(1);                                             \
    acc0[0][0] = MFMA_BF16(a0, b00, acc0[0][0],0,0,0);                         \
    acc0[0][1] = MFMA_BF16(a0, b01, acc0[0][1],0,0,0);                         \
    acc1[0][0] = MFMA_BF16(a0, b10, acc1[0][0],0,0,0);                         \
    acc1[0][1] = MFMA_BF16(a0, b11, acc1[0][1],0,0,0);                         \
    acc0[1][0] = MFMA_BF16(a1, b00, acc0[1][0],0,0,0);                         \
    acc0[1][1] = MFMA_BF16(a1, b01, acc0[1][1],0,0,0);                         \
    acc1[1][0] = MFMA_BF16(a1, b10, acc1[1][0],0,0,0);                         \
    acc1[1][1] = MFMA_BF16(a1, b11, acc1[1][1],0,0,0);                         \
    acc0[2][0] = MFMA_BF16(a2, b00, acc0[2][0],0,0,0);                         \
    acc0[2][1] = MFMA_BF16(a2, b01, acc0[2][1],0,0,0);                         \
    acc1[2][0] = MFMA_BF16(a2, b10, acc1[2][0],0,0,0);                         \
    acc1[2][1] = MFMA_BF16(a2, b11, acc1[2][1],0,0,0);                         \
    acc0[3][0] = MFMA_BF16(a3, b00, acc0[3][0],0,0,0);                         \
    acc0[3][1] = MFMA_BF16(a3, b01, acc0[3][1],0,0,0);                         \
    acc1[3][0] = MFMA_BF16(a3, b10, acc1[3][0],0,0,0);                         \
    acc1[3][1] = MFMA_BF16(a3, b11, acc1[3][1],0,0,0);                         \
    acc0[4][0] = MFMA_BF16(a4, b00, acc0[4][0],0,0,0);                         \
    acc0[4][1] = MFMA_BF16(a4, b01, acc0[4][1],0,0,0);                         \
    acc1[4][0] = MFMA_BF16(a4, b10, acc1[4][0],0,0,0);                         \
    acc1[4][1] = MFMA_BF16(a4, b11, acc1[4][1],0,0,0);                         \
    acc0[5][0] = MFMA_BF16(a5, b00, acc0[5][0],0,0,0);                         \
    acc0[5][1] = MFMA_BF16(a5, b01, acc0[5][1],0,0,0);                         \
    acc1[5][0] = MFMA_BF16(a5, b10, acc1[5][0],0,0,0);                         \
    acc1[5][1] = MFMA_BF16(a5, b11, acc1[5][1],0,0,0);                         \
    acc0[6][0] = MFMA_BF16(a6, b00, acc0[6][0],0,0,0);                         \
    acc0[6][1] = MFMA_BF16(a6, b01, acc0[6][1],0,0,0);                         \
    acc1[6][0] = MFMA_BF16(a6, b10, acc1[6][0],0,0,0);                         \
    acc1[6][1] = MFMA_BF16(a6, b11, acc1[6][1],0,0,0);                         \
    acc0[7][0] = MFMA_BF16(a7, b00, acc0[7][0],0,0,0);                         \
    acc0[7][1] = MFMA_BF16(a7, b01, acc0[7][1],0,0,0);                         \
    acc1[7][0] = MFMA_BF16(a7, b10, acc1[7][0],0,0,0);                         \
    acc1[7][1] = MFMA_BF16(a7, b11, acc1[7][1],0,0,0);                         \
    __builtin_amdgcn_s_setprio(0);                                             \
} while (0)

__global__ __launch_bounds__(128)
void bsl_mfma_kernel(const ushort_t* __restrict__ xc,
                     const ushort_t* __restrict__ wb,
                     const int* __restrict__ plist,
                     const int* __restrict__ pcnt,
                     float* __restrict__ out) {
    __shared__ ushort_t ringA[2][3][4096];   // per wave: 3 x 8 KB A slots
    __shared__ ushort_t ringB[2][3][2048];   // per wave: 3 x 4 KB B slots (2 blocks)
    __shared__ int      llist[2][PCAP];

    const int wg   = blockIdx.x;            // [0,512)
    const int q    = wg & 7;                // XCD residue -> slab group (A L2-pinned)
    const int i    = wg >> 3;               // [0,64)
    const int slab = q * 4 + (i & 3);       // [0,32): 128-token slab
    const int tid  = threadIdx.x;
    const int wv   = tid >> 6, lane = tid & 63;
    const int pair = (i >> 2) * 2 + wv;     // [0,32): row pair
    const int l15  = lane & 15, hi = lane >> 4;
    const int tok0 = slab * 128;

    const int cnt3 = pcnt[pair];

    // ---- list -> LDS (lgkm path)
    int lv0 = plist[pair * PCAP + lane];
    int lv1 = plist[pair * PCAP + lane + 64];
    int lv2 = plist[pair * PCAP + lane + 128];
    asm volatile("s_waitcnt vmcnt(0)" ::: "memory");
    llist[wv][lane] = lv0;
    llist[wv][lane + 64] = lv1;
    llist[wv][lane + 128] = lv2;
    int e0 = llist[wv][0], e1 = llist[wv][1];
    int ea = llist[wv][2], eb = llist[wv][3], ec = llist[wv][4];

    const ushort_t* xsrc = xc + lane * 8;
    const ushort_t* wsrc = wb + lane * 8;
    ushort_t* spA0 = &ringA[wv][0][0];
    ushort_t* spA1 = &ringA[wv][1][0];
    ushort_t* spA2 = &ringA[wv][2][0];
    ushort_t* spB0 = &ringB[wv][0][0];
    ushort_t* spB1 = &ringB[wv][1][0];
    ushort_t* spB2 = &ringB[wv][2][0];

    auto STAGE = [&](ushort_t* spA, ushort_t* spB, int e) {
        int eu  = __builtin_amdgcn_readfirstlane(e);
        int col = eu & 63;
        int n0  = (eu >> 6) & 0xFFF;
        int n1  = (eu >> 18) & 0xFFF;
        const ushort_t* as = xsrc + ((size_t)(col * 64 + 2 * slab) << 11);
        #pragma unroll
        for (int t = 0; t < 8; ++t) gll16(as + t * 512, spA + t * 512);
        const ushort_t* b0s = wsrc + ((size_t)n0 << 10);
        const ushort_t* b1s = wsrc + ((size_t)n1 << 10);
        gll16(b0s,       spB);
        gll16(b0s + 512, spB + 512);
        gll16(b1s,       spB + 1024);
        gll16(b1s + 512, spB + 1536);
    };

    f32x4 acc0[8][2], acc1[8][2];
    #pragma unroll
    for (int m = 0; m < 8; ++m) {
        acc0[m][0] = (f32x4){0.f,0.f,0.f,0.f}; acc0[m][1] = (f32x4){0.f,0.f,0.f,0.f};
        acc1[m][0] = (f32x4){0.f,0.f,0.f,0.f}; acc1[m][1] = (f32x4){0.f,0.f,0.f,0.f};
    }

    unsigned fbA0 = (unsigned)(size_t)&ringA[wv][0][0] + lane * 16;
    unsigned fbA1 = fbA0 + 8192;
    unsigned fbA2 = fbA0 + 16384;
    unsigned fbB0 = (unsigned)(size_t)&ringB[wv][0][0] + lane * 16;
    unsigned fbB1 = fbB0 + 4096;
    unsigned fbB2 = fbB0 + 8192;
    unsigned laddr = (unsigned)(size_t)&llist[wv][0] + 5 * 4;

    STAGE(spA0, spB0, e0);
    STAGE(spA1, spB1, e1);
    asm volatile("s_waitcnt vmcnt(0)" ::: "memory");
    __builtin_amdgcn_sched_barrier(0);

    for (int j = 0; j < cnt3; j += 3) {
        SUBITER(fbA0, fbB0, spA2, spB2, ea);   // compute slot0; stage entry j+2 -> slot2
        SUBITER(fbA1, fbB1, spA0, spB0, eb);   // compute slot1; stage entry j+3 -> slot0
        SUBITER(fbA2, fbB2, spA1, spB1, ec);   // compute slot2; stage entry j+4 -> slot1
    }
    asm volatile("s_waitcnt vmcnt(0) lgkmcnt(0)" ::: "memory");

    // C/D layout: col = lane&15, row = (lane>>4)*4 + reg  [HW-verified]
    const int oc0 = (pair * 2) * 32 + l15;
    #pragma unroll
    for (int m = 0; m < 8; ++m) {
        #pragma unroll
        for (int ns = 0; ns < 2; ++ns) {
            #pragma unroll
            for (int reg = 0; reg < 4; ++reg) {
                int token = tok0 + m * 16 + hi * 4 + reg;
                out[(size_t)token * 2048 + oc0 + ns * 16]      = acc0[m][ns][reg];
                out[(size_t)token * 2048 + oc0 + 32 + ns * 16] = acc1[m][ns][reg];
            }
        }
    }
}

extern "C" void kernel_launch(void* const* d_in, const int* in_sizes, int n_in,
                              void* d_out, int out_size, void* d_ws, size_t ws_size,
                              hipStream_t stream) {
    const float* x     = (const float*)d_in[0];
    const float* wblk  = (const float*)d_in[1];
    const int*   brows = (const int*)d_in[2];
    const int*   bcols = (const int*)d_in[3];
    float*       out   = (float*)d_out;

    char* ws = (char*)d_ws;
    ushort_t* xc     = (ushort_t*)(ws);                    // 16,777,216 B
    ushort_t* wb     = (ushort_t*)(ws + 16777216);         //  4,196,352 B (2049 blocks)
    int*      bucket = (int*)(ws + 20973568);              //     24,576 B (64 x 96)
    int*      bcnt   = (int*)(ws + 20998144);              //        256 B
    int*      plist  = (int*)(ws + 20998400);              //     24,576 B (32 x 192)
    int*      pcnt   = (int*)(ws + 21022976);              //        128 B

    // 1024 (x tiles) + 1024 (w cvt) + 1 (zero blk) + 16 (bucketize)
    prep_kernel<<<2065, 256, 0, stream>>>(x, wblk, brows, bcols, xc, wb, bucket, bcnt);
    prep2_kernel<<<32, 64, 0, stream>>>(bucket, bcnt, plist, pcnt);
    bsl_mfma_kernel<<<512, 128, 0, stream>>>(xc, wb, plist, pcnt, out);
}

// Round 15
// 62.997 us; speedup vs baseline: 1.1694x; 1.1694x over previous
//
#include <hip/hip_runtime.h>
#include <hip/hip_bf16.h>

typedef short short8 __attribute__((ext_vector_type(8)));
typedef float f32x4 __attribute__((ext_vector_type(4)));
typedef int   i32x4 __attribute__((ext_vector_type(4)));
typedef unsigned short ushort_t;
typedef unsigned short ushort4v __attribute__((ext_vector_type(4)));

#define NBLK   2048
#define ROWCAP 96
#define ZENT   (NBLK << 6)   // pad entry -> zero weight block, col 0
#define MFMA_BF16 __builtin_amdgcn_mfma_f32_16x16x32_bf16

__device__ __forceinline__ ushort_t f2bf(float f) {
    unsigned u = __float_as_uint(f);
    u += 0x7FFFu + ((u >> 16) & 1u);   // RTNE
    return (ushort_t)(u >> 16);
}
__device__ __forceinline__ void gll16(const void* g, void* l) {
    __builtin_amdgcn_global_load_lds(
        (const __attribute__((address_space(1))) unsigned*)g,
        (__attribute__((address_space(3))) unsigned*)l, 16, 0, 0);
}

// ================= prep (verbatim R8, passed) =================
__global__ __launch_bounds__(256)
void prep_kernel(const float* __restrict__ x, const float* __restrict__ wblk,
                 const int* __restrict__ brows, const int* __restrict__ bcols,
                 ushort_t* __restrict__ xc, ushort_t* __restrict__ wb,
                 int* __restrict__ bucket, int* __restrict__ bcnt) {
    __shared__ ushort_t pt[4][2048];
    const int bid = blockIdx.x, tid = threadIdx.x;
    const int wv = tid >> 6, lane = tid & 63;

    if (bid < 1024) {
        const int tc = bid * 4 + wv;
        const int cb = tc >> 6, t64 = tc & 63;
        #pragma unroll
        for (int it = 0; it < 8; ++it) {
            int row = it * 8 + (lane >> 3);
            const float* src = x + (size_t)(t64 * 64 + row) * 2048 + cb * 32 + (lane & 7) * 4;
            float4 v = *reinterpret_cast<const float4*>(src);
            ushort4v o; o.x = f2bf(v.x); o.y = f2bf(v.y); o.z = f2bf(v.z); o.w = f2bf(v.w);
            int m = row >> 4, l15v = row & 15, hi = (lane & 7) >> 1;
            int cc = m * 64 + hi * 16 + l15v;
            *reinterpret_cast<ushort4v*>(&pt[wv][cc * 8 + (lane & 1) * 4]) = o;
        }
        #pragma unroll
        for (int rr = 0; rr < 4; ++rr) {
            i32x4 d = *reinterpret_cast<const i32x4*>(&pt[wv][(rr * 64 + lane) * 8]);
            *reinterpret_cast<i32x4*>(xc + (size_t)tc * 2048 + (rr * 64 + lane) * 8) = d;
        }
    } else if (bid < 2048) {
        int d = (bid - 1024) * 256 + tid;
        int n = d >> 7, cc = d & 127;
        int nsub = cc >> 6, ln = cc & 63;
        int o_ = nsub * 16 + (ln & 15), kc = ln >> 4;
        const float* src = wblk + (size_t)n * 1024 + o_ * 32 + kc * 8;
        float4 v0 = *reinterpret_cast<const float4*>(src);
        float4 v1 = *reinterpret_cast<const float4*>(src + 4);
        short8 o8;
        o8[0] = f2bf(v0.x); o8[1] = f2bf(v0.y); o8[2] = f2bf(v0.z); o8[3] = f2bf(v0.w);
        o8[4] = f2bf(v1.x); o8[5] = f2bf(v1.y); o8[6] = f2bf(v1.z); o8[7] = f2bf(v1.w);
        reinterpret_cast<short8*>(wb)[d] = o8;
    } else if (bid == 2048) {
        if (tid < 128) {
            short8 z = (short8){0,0,0,0,0,0,0,0};
            reinterpret_cast<short8*>(wb + (size_t)NBLK * 1024)[tid] = z;
        }
    } else {
        const int r = (bid - 2049) * 4 + wv;
        const int per = NBLK / 64;
        const int base = lane * per;
        int cnt = 0;
        for (int k = 0; k < per; ++k) cnt += (brows[base + k] == r) ? 1 : 0;
        int sum = cnt;
        for (int d = 1; d < 64; d <<= 1) {
            int v = __shfl_up(sum, d, 64);
            if (lane >= d) sum += v;
        }
        int off = sum - cnt;
        for (int k = 0; k < per; ++k) {
            int n = base + k;
            if (brows[n] == r) bucket[r * ROWCAP + (off++)] = (n << 6) | bcols[n];
        }
        int total = __shfl(sum, 63, 64);
        if (lane < 8) bucket[r * ROWCAP + total + lane] = ZENT;
        if (lane == 0) bcnt[r] = total;
    }
}

// ================= main kernel (R13: R8 chassis + distance-3 B-in-registers) ==========
// 1024 WGs x 128 thr (2 waves). Wave job = (row r, 128-token slab), R8 XCD map.
// A: per-wave private depth-3 LDS ring (8 KB slots), gll16, stage-ahead 2.
// B: registers at pipeline distance 3 (covers L3 latency). 8 A-gll16 + 2 B-loads
// = 10 vm ops/subiter; counted vmcnt(10); zero barriers. This sits at ~93% of the
// measured ~13 TB/s L3-flow wall (640 MB flow / 52.6 us) — see R14 post-mortem.
#define DSR(d, a, o) asm volatile("ds_read_b128 %0, %1 offset:" #o : "=v"(d) : "v"(a))

#define SUBITER(FB, SPX, EA, BC0, BC1, EB) do {                                \
    short8 a0,a1,a2,a3,a4,a5,a6,a7;                                            \
    asm volatile("s_waitcnt vmcnt(10)" ::: "memory");                          \
    __builtin_amdgcn_sched_barrier(0);                                         \
    DSR(a0, FB, 0);    DSR(a1, FB, 1024); DSR(a2, FB, 2048); DSR(a3, FB, 3072);\
    DSR(a4, FB, 4096); DSR(a5, FB, 5120); DSR(a6, FB, 6144); DSR(a7, FB, 7168);\
    STAGE(SPX, EA);                                                            \
    asm volatile("ds_read_b32 %0, %1" : "=v"(EA) : "v"(laddr) : "memory");     \
    laddr += 4;                                                                \
    asm volatile("s_waitcnt lgkmcnt(0)" ::: "memory");                         \
    __builtin_amdgcn_sched_barrier(0);                                         \
    __builtin_amdgcn_s_setprio(1);                                             \
    acc[0][0] = MFMA_BF16(a0, BC0, acc[0][0], 0,0,0);                          \
    acc[0][1] = MFMA_BF16(a0, BC1, acc[0][1], 0,0,0);                          \
    acc[1][0] = MFMA_BF16(a1, BC0, acc[1][0], 0,0,0);                          \
    acc[1][1] = MFMA_BF16(a1, BC1, acc[1][1], 0,0,0);                          \
    acc[2][0] = MFMA_BF16(a2, BC0, acc[2][0], 0,0,0);                          \
    acc[2][1] = MFMA_BF16(a2, BC1, acc[2][1], 0,0,0);                          \
    acc[3][0] = MFMA_BF16(a3, BC0, acc[3][0], 0,0,0);                          \
    acc[3][1] = MFMA_BF16(a3, BC1, acc[3][1], 0,0,0);                          \
    acc[4][0] = MFMA_BF16(a4, BC0, acc[4][0], 0,0,0);                          \
    acc[4][1] = MFMA_BF16(a4, BC1, acc[4][1], 0,0,0);                          \
    acc[5][0] = MFMA_BF16(a5, BC0, acc[5][0], 0,0,0);                          \
    acc[5][1] = MFMA_BF16(a5, BC1, acc[5][1], 0,0,0);                          \
    acc[6][0] = MFMA_BF16(a6, BC0, acc[6][0], 0,0,0);                          \
    acc[6][1] = MFMA_BF16(a6, BC1, acc[6][1], 0,0,0);                          \
    acc[7][0] = MFMA_BF16(a7, BC0, acc[7][0], 0,0,0);                          \
    acc[7][1] = MFMA_BF16(a7, BC1, acc[7][1], 0,0,0);                          \
    __builtin_amdgcn_s_setprio(0);                                             \
    {   /* reload this B set for entry (j+3): consumed above, WAR-safe */      \
        int eu = __builtin_amdgcn_readfirstlane(EB);                           \
        const ushort_t* bp = wb + ((size_t)(unsigned)(eu >> 6) << 10) + lane * 8; \
        BC0 = *reinterpret_cast<const short8*>(bp);                            \
        BC1 = *reinterpret_cast<const short8*>(bp + 512);                      \
    }                                                                          \
    __builtin_amdgcn_sched_barrier(0);                                         \
} while (0)

__global__ __launch_bounds__(128)
void bsl_mfma_kernel(const ushort_t* __restrict__ xc,
                     const ushort_t* __restrict__ wb,
                     const int* __restrict__ bucket,
                     const int* __restrict__ bcnt,
                     float* __restrict__ out) {
    __shared__ ushort_t ring[2][3][4096];   // per wave: 3 x 8 KB A slots (48 KB)
    __shared__ int      llist[2][96];

    const int wg   = blockIdx.x;            // [0,1024)
    const int q    = wg & 7;                // XCD residue -> slab group (R8 map)
    const int i    = wg >> 3;               // [0,128)
    const int slab = q * 4 + (i & 3);       // [0,32): 128-token slab, L2-pinned A
    const int tid  = threadIdx.x;
    const int wv   = tid >> 6, lane = tid & 63;
    const int r    = (i >> 2) * 2 + wv;     // [0,64): output row-block
    const int l15  = lane & 15, hi = lane >> 4;
    const int tok0 = slab * 128;

    const int cnt = bcnt[r];

    // ---- list -> LDS (lgkm path; keeps vmcnt clean in the loop)
    int lv = 0;
    if (lane < ROWCAP) lv = bucket[r * ROWCAP + lane];
    asm volatile("s_waitcnt vmcnt(0)" ::: "memory");
    if (lane < ROWCAP) llist[wv][lane] = lv;
    int e0 = llist[wv][0], e1 = llist[wv][1];
    int ea = llist[wv][2], eb = llist[wv][3], ec = llist[wv][4];

    const ushort_t* xsrc = xc + lane * 8;
    ushort_t* sp0 = &ring[wv][0][0];
    ushort_t* sp1 = &ring[wv][1][0];
    ushort_t* sp2 = &ring[wv][2][0];

    auto STAGE = [&](ushort_t* sp, int e) {
        int eu = __builtin_amdgcn_readfirstlane(e);
        const ushort_t* as = xsrc + ((size_t)((eu & 63) * 64 + 2 * slab) << 11);
        #pragma unroll
        for (int t = 0; t < 8; ++t) gll16(as + t * 512, sp + t * 512);
    };

    f32x4 acc[8][2];
    #pragma unroll
    for (int m = 0; m < 8; ++m) {
        acc[m][0] = (f32x4){0.f, 0.f, 0.f, 0.f};
        acc[m][1] = (f32x4){0.f, 0.f, 0.f, 0.f};
    }

    unsigned fb0 = (unsigned)(size_t)&ring[wv][0][0] + lane * 16;
    unsigned fb1 = fb0 + 8192;
    unsigned fb2 = fb0 + 16384;
    unsigned laddr = (unsigned)(size_t)&llist[wv][0] + 5 * 4;

    // prologue: stage A(0),A(1); preload B(0),B(1),B(2) into the 3 reg sets
    STAGE(sp0, e0);
    STAGE(sp1, e1);
    short8 B00, B01, B10, B11, B20, B21;
    {
        int eu = __builtin_amdgcn_readfirstlane(e0);
        const ushort_t* bp = wb + ((size_t)(unsigned)(eu >> 6) << 10) + lane * 8;
        B00 = *reinterpret_cast<const short8*>(bp);
        B01 = *reinterpret_cast<const short8*>(bp + 512);
        eu = __builtin_amdgcn_readfirstlane(e1);
        bp = wb + ((size_t)(unsigned)(eu >> 6) << 10) + lane * 8;
        B10 = *reinterpret_cast<const short8*>(bp);
        B11 = *reinterpret_cast<const short8*>(bp + 512);
        eu = __builtin_amdgcn_readfirstlane(ea);
        bp = wb + ((size_t)(unsigned)(eu >> 6) << 10) + lane * 8;
        B20 = *reinterpret_cast<const short8*>(bp);
        B21 = *reinterpret_cast<const short8*>(bp + 512);
    }
    asm volatile("s_waitcnt vmcnt(0)" ::: "memory");
    __builtin_amdgcn_sched_barrier(0);

    const int cnt3 = ((cnt + 2) / 3) * 3;   // pads are zero-W blocks
    for (int j = 0; j < cnt3; j += 3) {
        SUBITER(fb0, sp2, ea, B00, B01, eb);  // compute0: A ring0 + Bset0; stage A(j+2); load B(j+3)->set0
        SUBITER(fb1, sp0, eb, B10, B11, ec);  // compute1: stage A(j+3); load B(j+4)->set1
        SUBITER(fb2, sp1, ec, B20, B21, ea);  // compute2: stage A(j+4); load B(j+5)->set2
    }
    asm volatile("s_waitcnt vmcnt(0) lgkmcnt(0)" ::: "memory");

    // C/D layout: col = lane&15, row = (lane>>4)*4 + reg  [HW-verified]
    const int outc = r * 32 + l15;
    #pragma unroll
    for (int m = 0; m < 8; ++m) {
        #pragma unroll
        for (int ns = 0; ns < 2; ++ns) {
            #pragma unroll
            for (int reg = 0; reg < 4; ++reg) {
                int token = tok0 + m * 16 + hi * 4 + reg;
                out[(size_t)token * 2048 + outc + ns * 16] = acc[m][ns][reg];
            }
        }
    }
}

extern "C" void kernel_launch(void* const* d_in, const int* in_sizes, int n_in,
                              void* d_out, int out_size, void* d_ws, size_t ws_size,
                              hipStream_t stream) {
    const float* x     = (const float*)d_in[0];
    const float* wblk  = (const float*)d_in[1];
    const int*   brows = (const int*)d_in[2];
    const int*   bcols = (const int*)d_in[3];
    float*       out   = (float*)d_out;

    char* ws = (char*)d_ws;
    ushort_t* xc     = (ushort_t*)(ws);                    // 16,777,216 B
    ushort_t* wb     = (ushort_t*)(ws + 16777216);         //  4,196,352 B (2049 blocks)
    int*      bucket = (int*)(ws + 20973568);              //     24,576 B (64 x 96)
    int*      bcnt   = (int*)(ws + 20998144);              //        256 B

    // 1024 (x tiles) + 1024 (w cvt) + 1 (zero blk) + 16 (bucketize)
    prep_kernel<<<2065, 256, 0, stream>>>(x, wblk, brows, bcols, xc, wb, bucket, bcnt);
    bsl_mfma_kernel<<<1024, 128, 0, stream>>>(xc, wb, bucket, bcnt, out);
}